// Round 15
// baseline (483.313 us; speedup 1.0000x reference)
//
#include <hip/hip_runtime.h>
#include <hip/hip_bf16.h>

#define BB 2
#define TT 12
#define NN 20000
#define FF 9
#define HH 64
#define EE 200000
#define NP 128   // padded slots per node for 9-dim tensors

typedef __hip_bfloat16 bf;
typedef __attribute__((ext_vector_type(8))) short s8v;   // 8 bf16 (4 VGPRs)
typedef __attribute__((ext_vector_type(4))) float f4v;

// ---- big buffers ---------------------------------------------------------
// xp/a9/z9: bf16 PAIR-PACKED u32, HALF layout: idx = n*128 + h*64 + (t-6h)*9 + f
//   (half h = t/6; slots 54..63 of each half are zero pad; 256B gather blocks)
// x9/r9: fp32, flat layout: idx = n*128 + t*9 + f (slots 108..127 pad)
__device__ unsigned g_xa[TT*NN*HH];   // 61.4 MB conv1 out, bf16 pair [t][n][64]
__device__ unsigned g_ag[TT*NN*HH];   // 61.4 MB aggregation (layer2) [t][n][64]
__device__ float2   g_x9[(size_t)NN*NP];   // 20.5 MB conv3 out (fp32)
__device__ unsigned g_xp[(size_t)NN*NP];   // 10.2 MB input x (bf16 pair, halves)
__device__ unsigned g_z9[(size_t)NN*NP];   // 10.2 MB x2@W3l (bf16 pair, halves)
__device__ float2   g_r9[(size_t)NN*NP];   // 20.5 MB x2@W3r+b3 (fp32)
__device__ unsigned g_a9[(size_t)NN*NP];   // 10.2 MB layer-1 agg (bf16 pair, halves)
__device__ int      g_rp[NN+1];
__device__ int      g_cnt[NN];
__device__ int      g_csrc[EE];
__device__ float    g_cw[EE];
__device__ float    g_cvec[32];

__device__ __forceinline__ float lo2f(unsigned u){ unsigned v=u<<16; float f; __builtin_memcpy(&f,&v,4); return f; }
__device__ __forceinline__ float hi2f(unsigned u){ unsigned v=u&0xffff0000u; float f; __builtin_memcpy(&f,&v,4); return f; }
__device__ __forceinline__ unsigned short f2us(float f){ bf h=__float2bfloat16(f); unsigned short u; __builtin_memcpy(&u,&h,2); return u; }
__device__ __forceinline__ unsigned pack2(float a0, float a1){ return (unsigned)f2us(a0) | ((unsigned)f2us(a1)<<16); }
__device__ __forceinline__ float elu(float x){ return x>0.f ? x : expm1f(x); }

// ---- CSR build -----------------------------------------------------------
__global__ void k_zero(){
  int i = blockIdx.x*256 + threadIdx.x;
  if(i < NN) g_cnt[i] = 0;
}
__global__ void k_count(const int* __restrict__ dst){
  int e = blockIdx.x*256 + threadIdx.x;
  if(e < EE) atomicAdd(&g_cnt[dst[e]], 1);
}
// scan + re-zero g_cnt + head precompute (all single-block work fused)
__global__ void k_scan(const float* __restrict__ encW, const float* __restrict__ encb,
                       const float* __restrict__ decW, const float* __restrict__ decb,
                       const float* __restrict__ te){
  __shared__ int part[256];
  __shared__ float c[19];
  const int CH = 79;
  int t = threadIdx.x;
  int base = t*CH;
  int s = 0;
  for(int i=0;i<CH;i++){ int idx=base+i; if(idx<NN) s += g_cnt[idx]; }
  part[t] = s; __syncthreads();
  for(int off=1; off<256; off<<=1){
    int v = (t>=off) ? part[t-off] : 0;
    __syncthreads();
    part[t] += v;
    __syncthreads();
  }
  int run = (t==0) ? 0 : part[t-1];
  for(int i=0;i<CH;i++){
    int idx=base+i;
    if(idx<NN){ run += g_cnt[idx]; g_rp[idx+1] = run; g_cnt[idx] = 0; }
  }
  if(t==0) g_rp[0] = 0;
  // ---- head ----
  if(t < 18){ float v=0.f; for(int j=0;j<64;j++) v += encW[t*64+j]*decW[j]; c[t]=v; }
  if(t == 18){ float v=decb[0]; for(int j=0;j<64;j++) v += encb[j]*decW[j]; c[18]=v; }
  __syncthreads();
  if(t < FF) g_cvec[t] = c[t];
  if(t < BB){ float v=c[18]; for(int k=0;k<FF;k++) v += te[t*FF+k]*c[9+k]; g_cvec[FF+t]=v; }
}
__global__ void k_fill(const int* __restrict__ dst, const int* __restrict__ src,
                       const float* __restrict__ ew){
  int e = blockIdx.x*256 + threadIdx.x;
  if(e >= EE) return;
  int d = dst[e];
  int pos = g_rp[d] + atomicAdd(&g_cnt[d], 1);
  g_csrc[pos] = src[e];
  g_cw[pos]   = ew[e];
}

// ---- pack input: xp half layout = bf16pair(x[b0], x[b1]) ----------------
__global__ void k_pack(const float* __restrict__ g){
  long i = (long)blockIdx.x*256 + threadIdx.x;
  if(i < (long)TT*NN*FF){
    int t = (int)(i / (NN*FF));
    int r = (int)(i - (long)t*NN*FF);
    int n = r / FF;
    int f = r - n*FF;
    int h = t/6, tl = t - 6*h;
    g_xp[(size_t)n*NP + h*64 + tl*9 + f] = pack2(g[i], g[(long)TT*NN*FF + i]);
  }
}

// ---- agg1: half-block gather of x -> g_a9; XCD dst-partitioned ----------
// per half: 256B blocks, per-XCD source working set ~3.6MB (fits 4MB L2)
__global__ void k_agg1(){
  int tid = threadIdx.x;
  int lane = tid & 63;
  int grp  = lane >> 4;
  int sub  = lane & 15;
  int xcd = blockIdx.x & 7;
  int lb  = blockIdx.x >> 3;
  int wid = (lb*256 + tid) >> 6;
  int nwx = (gridDim.x >> 3)*4;
  const int SEG = NN/8;                // 2500
  int lo = xcd*SEG, hi = lo + SEG;
  for(int h=0; h<2; h++){
    const unsigned* __restrict__ srcb = g_xp + h*64;
    for(int n=lo+wid; n<hi; n+=nwx){
      int r0=g_rp[n], r1=g_rp[n+1];
      float inv = 1.f/fmaxf((float)(r1-r0), 1.f);
      float acc[8];
      #pragma unroll
      for(int s=0;s<8;s++) acc[s]=0.f;
      for(int base=r0; base<r1; base+=64){
        int cnt = min(64, r1-base);
        int ms = 0; float mw = 0.f;
        if(lane < cnt){ ms = g_csrc[base+lane]; mw = g_cw[base+lane]; }
        for(int k=0;k<cnt;k+=4){
          int   sg = __shfl(ms, k+grp, 64);
          float wg = __shfl(mw, k+grp, 64);
          const uint4 v = *(reinterpret_cast<const uint4*>(srcb + (size_t)sg*NP) + sub);
          acc[0]+=wg*lo2f(v.x); acc[1]+=wg*hi2f(v.x);
          acc[2]+=wg*lo2f(v.y); acc[3]+=wg*hi2f(v.y);
          acc[4]+=wg*lo2f(v.z); acc[5]+=wg*hi2f(v.z);
          acc[6]+=wg*lo2f(v.w); acc[7]+=wg*hi2f(v.w);
        }
      }
      #pragma unroll
      for(int s=0;s<8;s++){
        acc[s] += __shfl_xor(acc[s],16,64);
        acc[s] += __shfl_xor(acc[s],32,64);
      }
      if(grp == 0){
        uint4 w;
        w.x = pack2(acc[0]*inv, acc[1]*inv);
        w.y = pack2(acc[2]*inv, acc[3]*inv);
        w.z = pack2(acc[4]*inv, acc[5]*inv);
        w.w = pack2(acc[6]*inv, acc[7]*inv);
        *(reinterpret_cast<uint4*>(g_a9 + (size_t)n*NP + h*64) + sub) = w;
      }
    }
  }
}

// ---- gemm1 (all t): ELU([AGG1|X]@[W1l;W1r]+b1) -> g_xa, K=18 pad 32 -----
__global__ __launch_bounds__(256) void k_gemm1(const float* __restrict__ Wl,
                                               const float* __restrict__ bias,
                                               const float* __restrict__ Wr){
  int t = blockIdx.y;
  int th = t/6, ttl = t - 6*th;
  int hoff = th*64 + ttl*9;
  __shared__ unsigned short sW[32*65];
  int tid = threadIdx.x;
  for(int i=tid; i<32*64; i+=256){
    int r = i >> 6, c = i & 63;
    float v = 0.f;
    if(r < FF)        v = Wl[(size_t)t*FF*HH + r*HH + c];
    else if(r < 2*FF) v = Wr[(size_t)t*FF*HH + (r-FF)*HH + c];
    sW[r*65+c] = f2us(v);
  }
  __syncthreads();
  int lane = tid & 63, wave = tid >> 6;
  int quad = lane >> 4, col = lane & 15;
  int base16 = blockIdx.x*64 + wave*16;
  if(base16 >= NN) return;
  size_t tb = (size_t)t*NN;
  int node = base16 + col;
  s8v A0, A1;
  #pragma unroll
  for(int j=0;j<8;j++){
    int k = quad*8 + j;
    unsigned u = 0;
    if(k < FF)        u = g_a9[(size_t)node*NP + hoff + k];
    else if(k < 2*FF) u = g_xp[(size_t)node*NP + hoff + (k-FF)];
    A0[j] = (short)(u & 0xffffu);
    A1[j] = (short)(u >> 16);
  }
  #pragma unroll
  for(int nt=0; nt<4; nt++){
    f4v c0 = {0.f,0.f,0.f,0.f}, c1 = {0.f,0.f,0.f,0.f};
    s8v B;
    #pragma unroll
    for(int j=0;j<8;j++)
      B[j] = (short)sW[(quad*8+j)*65 + nt*16+col];
    c0 = __builtin_amdgcn_mfma_f32_16x16x32_bf16(A0, B, c0, 0, 0, 0);
    c1 = __builtin_amdgcn_mfma_f32_16x16x32_bf16(A1, B, c1, 0, 0, 0);
    float bn = bias[t*HH + nt*16 + col];
    #pragma unroll
    for(int reg=0; reg<4; reg++){
      int nd = base16 + quad*4 + reg;
      g_xa[(tb+nd)*HH + nt*16 + col] = pack2(elu(c0[reg]+bn), elu(c1[reg]+bn));
    }
  }
}

// ---- agg (all t): 64-dim gather from g_xa; XCD-range partitioned --------
__global__ void k_agg_all(){
  const unsigned* __restrict__ src = g_xa;
  int tid = threadIdx.x;
  int lane = tid & 63;
  int grp  = lane >> 4;
  int sub  = lane & 15;
  const int TOT = TT*NN;
  const int SEG = TOT/8;               // 30000
  int xcd = blockIdx.x & 7;            // gfx950 round-robin block->XCD
  int lb  = blockIdx.x >> 3;
  int wid = (lb*256 + tid) >> 6;
  int nwx = (gridDim.x >> 3)*4;
  int lo = xcd*SEG, hi = lo + SEG;
  for(int idx=lo+wid; idx<hi; idx+=nwx){
    unsigned ut = (unsigned)idx / NN;
    int n = idx - (int)(ut*NN);
    size_t tb = (size_t)ut*NN;
    const unsigned* __restrict__ rowp = src + tb*HH + (sub<<2);
    int r0=g_rp[n], r1=g_rp[n+1];
    float inv = 1.f/fmaxf((float)(r1-r0), 1.f);
    float p0[4]={0.f,0.f,0.f,0.f}, p1[4]={0.f,0.f,0.f,0.f};
    for(int base=r0; base<r1; base+=64){
      int cnt = min(64, r1-base);
      int ms = 0; float mw = 0.f;
      if(lane < cnt){ ms = g_csrc[base+lane]; mw = g_cw[base+lane]; }
      for(int k=0;k<cnt;k+=4){
        int   sg = __shfl(ms, k+grp, 64);
        float wg = __shfl(mw, k+grp, 64);
        const uint4 v = *reinterpret_cast<const uint4*>(rowp + (size_t)sg*HH);
        p0[0]+=wg*lo2f(v.x); p1[0]+=wg*hi2f(v.x);
        p0[1]+=wg*lo2f(v.y); p1[1]+=wg*hi2f(v.y);
        p0[2]+=wg*lo2f(v.z); p1[2]+=wg*hi2f(v.z);
        p0[3]+=wg*lo2f(v.w); p1[3]+=wg*hi2f(v.w);
      }
    }
    #pragma unroll
    for(int q=0;q<4;q++){
      p0[q] += __shfl_xor(p0[q],16,64); p1[q] += __shfl_xor(p1[q],16,64);
      p0[q] += __shfl_xor(p0[q],32,64); p1[q] += __shfl_xor(p1[q],32,64);
    }
    if(lane < 16){
      uint4 o;
      o.x = pack2(p0[0]*inv, p1[0]*inv);
      o.y = pack2(p0[1]*inv, p1[1]*inv);
      o.z = pack2(p0[2]*inv, p1[2]*inv);
      o.w = pack2(p0[3]*inv, p1[3]*inv);
      *reinterpret_cast<uint4*>(g_ag + (tb + (size_t)n)*HH + (lane<<2)) = o;
    }
  }
}

// ---- gemm23 (all t): fused conv2 + projection. ---------------------------
__global__ __launch_bounds__(256) void k_gemm23(const float* __restrict__ W2l,
                                                const float* __restrict__ b2,
                                                const float* __restrict__ W2r,
                                                const float* __restrict__ W3l,
                                                const float* __restrict__ b3,
                                                const float* __restrict__ W3r){
  int t = blockIdx.y;
  int th = t/6, ttl = t - 6*th;
  int hoff = th*64 + ttl*9;
  __shared__ unsigned short sW2[128*65];  // 16.6 KB bf16
  __shared__ unsigned short sW3[128*10];  // 2.6 KB bf16
  __shared__ unsigned sXB[64*66];         // 16.9 KB packed bf16-pair xb tile
  int tid = threadIdx.x;
  for(int i=tid; i<64*64; i+=256){
    int r = i >> 6, c = i & 63;
    sW2[r*65+c]      = f2us(W2l[(size_t)t*4096 + i]);
    sW2[(r+64)*65+c] = f2us(W2r[(size_t)t*4096 + i]);
  }
  for(int i=tid; i<64*FF; i+=256){
    int r = i/FF, c = i - r*FF;
    sW3[r*10+c]      = f2us(W3l[(size_t)t*HH*FF + i]);
    sW3[(r+64)*10+c] = f2us(W3r[(size_t)t*HH*FF + i]);
  }
  __syncthreads();
  int lane = tid & 63, wave = tid >> 6;
  int quad = lane >> 4, col = lane & 15;
  int base16 = blockIdx.x*64 + wave*16;
  if(base16 >= NN) return;
  size_t tb = (size_t)t*NN;
  // ---- stage A: conv2 ----
  {
    int nodeA = base16 + col;
    s8v A0[4], A1[4];
    #pragma unroll
    for(int ks=0; ks<4; ks++){
      const unsigned* srcb = (ks < 2) ? g_ag : g_xa;
      int koff = (ks & 1)*32 + quad*8;
      const uint4 u = *reinterpret_cast<const uint4*>(srcb + (tb+nodeA)*HH + koff);
      const uint4 v = *reinterpret_cast<const uint4*>(srcb + (tb+nodeA)*HH + koff + 4);
      unsigned uu[8] = {u.x,u.y,u.z,u.w,v.x,v.y,v.z,v.w};
      #pragma unroll
      for(int j=0;j<8;j++){
        A0[ks][j] = (short)(uu[j] & 0xffffu);
        A1[ks][j] = (short)(uu[j] >> 16);
      }
    }
    #pragma unroll
    for(int nt=0; nt<4; nt++){
      f4v c0 = {0.f,0.f,0.f,0.f}, c1 = {0.f,0.f,0.f,0.f};
      #pragma unroll
      for(int ks=0; ks<4; ks++){
        s8v B;
        #pragma unroll
        for(int j=0;j<8;j++)
          B[j] = (short)sW2[(ks*32+quad*8+j)*65 + nt*16+col];
        c0 = __builtin_amdgcn_mfma_f32_16x16x32_bf16(A0[ks], B, c0, 0, 0, 0);
        c1 = __builtin_amdgcn_mfma_f32_16x16x32_bf16(A1[ks], B, c1, 0, 0, 0);
      }
      float bn = b2[t*HH + nt*16 + col];
      #pragma unroll
      for(int reg=0; reg<4; reg++){
        int nl = wave*16 + quad*4 + reg;          // wave-private rows
        sXB[nl*66 + nt*16 + col] = pack2(elu(c0[reg]+bn), elu(c1[reg]+bn));
      }
    }
  }
  // wave-private tile: each wave reads only rows it wrote; no barrier needed.
  // ---- stage B: project to 9-dim ----
  {
    f4v z0={0.f,0.f,0.f,0.f}, z1={0.f,0.f,0.f,0.f};
    f4v r0={0.f,0.f,0.f,0.f}, r1={0.f,0.f,0.f,0.f};
    int nlA = wave*16 + col;
    #pragma unroll
    for(int ks=0; ks<2; ks++){
      int koff = ks*32 + quad*8;
      s8v A0, A1, Bl, Br;
      #pragma unroll
      for(int j=0;j<8;j++){
        unsigned u = sXB[nlA*66 + koff + j];
        A0[j] = (short)(u & 0xffffu);
        A1[j] = (short)(u >> 16);
        int row = ks*32 + quad*8 + j;
        Bl[j] = (col < FF) ? (short)sW3[row*10 + col]      : (short)0;
        Br[j] = (col < FF) ? (short)sW3[(row+64)*10 + col] : (short)0;
      }
      z0 = __builtin_amdgcn_mfma_f32_16x16x32_bf16(A0, Bl, z0, 0, 0, 0);
      z1 = __builtin_amdgcn_mfma_f32_16x16x32_bf16(A1, Bl, z1, 0, 0, 0);
      r0 = __builtin_amdgcn_mfma_f32_16x16x32_bf16(A0, Br, r0, 0, 0, 0);
      r1 = __builtin_amdgcn_mfma_f32_16x16x32_bf16(A1, Br, r1, 0, 0, 0);
    }
    if(col < FF){
      float bn = b3[t*FF + col];
      #pragma unroll
      for(int reg=0; reg<4; reg++){
        int node = base16 + quad*4 + reg;
        g_z9[(size_t)node*NP + hoff + col] = pack2(z0[reg], z1[reg]);
        float2 orr; orr.x = r0[reg]+bn; orr.y = r1[reg]+bn;
        g_r9[(size_t)node*NP + t*FF + col] = orr;
      }
    }
  }
}

// ---- agg9f: half-block gather of Z, + R, ELU -> g_x9; XCD-partitioned ---
__global__ void k_agg9f(){
  int tid = threadIdx.x;
  int lane = tid & 63;
  int grp  = lane >> 4;
  int sub  = lane & 15;
  int xcd = blockIdx.x & 7;
  int lb  = blockIdx.x >> 3;
  int wid = (lb*256 + tid) >> 6;
  int nwx = (gridDim.x >> 3)*4;
  const int SEG = NN/8;                // 2500
  int lo = xcd*SEG, hi = lo + SEG;
  for(int h=0; h<2; h++){
    const unsigned* __restrict__ srcb = g_z9 + h*64;
    for(int n=lo+wid; n<hi; n+=nwx){
      int r0=g_rp[n], r1=g_rp[n+1];
      float inv = 1.f/fmaxf((float)(r1-r0), 1.f);
      float acc[8];
      #pragma unroll
      for(int s=0;s<8;s++) acc[s]=0.f;
      for(int base=r0; base<r1; base+=64){
        int cnt = min(64, r1-base);
        int ms = 0; float mw = 0.f;
        if(lane < cnt){ ms = g_csrc[base+lane]; mw = g_cw[base+lane]; }
        for(int k=0;k<cnt;k+=4){
          int   sg = __shfl(ms, k+grp, 64);
          float wg = __shfl(mw, k+grp, 64);
          const uint4 v = *(reinterpret_cast<const uint4*>(srcb + (size_t)sg*NP) + sub);
          acc[0]+=wg*lo2f(v.x); acc[1]+=wg*hi2f(v.x);
          acc[2]+=wg*lo2f(v.y); acc[3]+=wg*hi2f(v.y);
          acc[4]+=wg*lo2f(v.z); acc[5]+=wg*hi2f(v.z);
          acc[6]+=wg*lo2f(v.w); acc[7]+=wg*hi2f(v.w);
        }
      }
      #pragma unroll
      for(int s=0;s<8;s++){
        acc[s] += __shfl_xor(acc[s],16,64);
        acc[s] += __shfl_xor(acc[s],32,64);
      }
      if(grp == 0){
        #pragma unroll
        for(int k=0;k<4;k++){
          int hs = sub*4 + k;            // half-slot
          if(hs < 54){
            int gslot = 54*h + hs;       // = t*9+f
            float2 r = g_r9[(size_t)n*NP + gslot];
            float2 o;
            o.x = elu(acc[2*k]*inv   + r.x);
            o.y = elu(acc[2*k+1]*inv + r.y);
            g_x9[(size_t)n*NP + gslot] = o;
          }
        }
      }
    }
  }
}

// ---- k_gru_fused: feature-parallel GRU, gix fused in-register -----------
__global__ __launch_bounds__(256) void k_gru_fused(const float* __restrict__ g,
                          const float* __restrict__ Wih, const float* __restrict__ Whh,
                          const float* __restrict__ bih, const float* __restrict__ bhh,
                          float* __restrict__ out){
  __shared__ float sWih[TT*FF*27];   // 11664 B
  __shared__ float sWhh[TT*FF*27];   // 11664 B
  __shared__ float sbih[TT*27], sbhh[TT*27];
  int tid = threadIdx.x;
  for(int i=tid;i<TT*FF*27;i+=256){ sWih[i]=Wih[i]; sWhh[i]=Whh[i]; }
  for(int i=tid;i<TT*27;i+=256){ sbih[i]=bih[i]; sbhh[i]=bhh[i]; }
  __syncthreads();
  int lane = tid & 63;
  int wv   = tid >> 6;
  int p    = lane / 9;               // 0..6 live, p==7 is the idle lane 63
  int f    = lane - p*9;
  int gbase = p*9;
  int id = (blockIdx.x*4 + wv)*7 + p;
  bool valid = (p < 7) && (id < BB*NN);
  int b = 0, n = 0;
  if(valid){ b = (id >= NN) ? 1 : 0; n = id - b*NN; }
  float c9[FF];
  #pragma unroll
  for(int i=0;i<FF;i++) c9[i] = g_cvec[i];
  float cb = g_cvec[FF+b];
  float h = 0.f;
  float hs[FF];
  #pragma unroll
  for(int i=0;i<FF;i++) hs[i] = 0.f;
  for(int t=0;t<TT;t++){
    float x = 0.f;
    if(valid){
      float2 xf = g_x9[(size_t)n*NP + t*FF + f];
      x = b ? xf.y : xf.x;
    }
    float xs[FF];
    #pragma unroll
    for(int i=0;i<FF;i++) xs[i] = __shfl(x, gbase+i, 64);
    const float* wi = &sWih[t*FF*27];
    const float* wh = &sWhh[t*FF*27];
    float gir = sbih[t*27+f], giz = sbih[t*27+9+f], gin = sbih[t*27+18+f];
    float ghr = sbhh[t*27+f], ghz = sbhh[t*27+9+f], ghn = sbhh[t*27+18+f];
    #pragma unroll
    for(int i=0;i<FF;i++){
      float xi = xs[i], hi = hs[i];
      gir += xi*wi[i*27+f];    giz += xi*wi[i*27+9+f];    gin += xi*wi[i*27+18+f];
      ghr += hi*wh[i*27+f];    ghz += hi*wh[i*27+9+f];    ghn += hi*wh[i*27+18+f];
    }
    float r = 1.f/(1.f+__expf(-(gir+ghr)));
    float z = 1.f/(1.f+__expf(-(giz+ghz)));
    float nv = tanhf(gin + r*ghn);
    h = (1.f-z)*nv + z*h;
    #pragma unroll
    for(int i=0;i<FF;i++) hs[i] = __shfl(h, gbase+i, 64);
    if(valid && f == 0){
      float acc = cb;
      #pragma unroll
      for(int i=0;i<FF;i++) acc += hs[i]*c9[i];
      size_t gidx = (size_t)(b*TT+t)*NN + n;
      float m = (g[gidx*FF] != 0.f) ? 1.f : 0.f;
      out[gidx] = acc*m;
    }
  }
}

extern "C" void kernel_launch(void* const* d_in, const int* in_sizes, int n_in,
                              void* d_out, int out_size, void* d_ws, size_t ws_size,
                              hipStream_t stream){
  const float* g    = (const float*)d_in[0];
  const float* te   = (const float*)d_in[1];
  const float* ew   = (const float*)d_in[3];
  const int* esrc = (const int*)d_in[4];
  const int* edst = (const int*)d_in[5];
  const float* W1l=(const float*)d_in[6];  const float* b1 =(const float*)d_in[7];  const float* W1r=(const float*)d_in[8];
  const float* W2l=(const float*)d_in[9];  const float* b2 =(const float*)d_in[10]; const float* W2r=(const float*)d_in[11];
  const float* W3l=(const float*)d_in[12]; const float* b3 =(const float*)d_in[13]; const float* W3r=(const float*)d_in[14];
  const float* Wih=(const float*)d_in[15]; const float* Whh=(const float*)d_in[16];
  const float* bih=(const float*)d_in[17]; const float* bhh=(const float*)d_in[18];
  const float* encW=(const float*)d_in[19]; const float* encb=(const float*)d_in[20];
  const float* decW=(const float*)d_in[21]; const float* decb=(const float*)d_in[22];
  float* out = (float*)d_out;

  k_zero <<<(NN+255)/256, 256, 0, stream>>>();
  k_count<<<(EE+255)/256, 256, 0, stream>>>(edst);
  k_scan <<<1, 256, 0, stream>>>(encW, encb, decW, decb, te);
  k_fill <<<(EE+255)/256, 256, 0, stream>>>(edst, esrc, ew);
  k_pack <<<((long)TT*NN*FF+255)/256, 256, 0, stream>>>(g);

  dim3 ggm((NN+63)/64, TT);
  k_agg1<<<2048, 256, 0, stream>>>();
  k_gemm1<<<ggm, 256, 0, stream>>>(W1l, b1, W1r);
  k_agg_all<<<2048, 256, 0, stream>>>();
  k_gemm23<<<ggm, 256, 0, stream>>>(W2l, b2, W2r, W3l, b3, W3r);
  k_agg9f<<<2048, 256, 0, stream>>>();
  // pairs = BB*NN; 28 pairs per 256-thread block (4 waves x 7)
  int nblk = (BB*NN + 27) / 28;
  k_gru_fused<<<nblk, 256, 0, stream>>>(g, Wih, Whh, bih, bhh, out);
}

// Round 16
// 474.569 us; speedup vs baseline: 1.0184x; 1.0184x over previous
//
#include <hip/hip_runtime.h>
#include <hip/hip_bf16.h>

#define BB 2
#define TT 12
#define NN 20000
#define FF 9
#define HH 64
#define EE 200000
#define NP 128   // padded slots per node for 9-dim tensors (12*9=108 used)

typedef __hip_bfloat16 bf;
typedef __attribute__((ext_vector_type(8))) short s8v;   // 8 bf16 (4 VGPRs)
typedef __attribute__((ext_vector_type(4))) float f4v;

// ---- big buffers: all-timestep activations (static device globals) -------
// 9-dim tensors are [n][NP] slots (slot = t*9+f, pad 108..127 stays zero).
// xp/a9/z9 are bf16 PAIR-PACKED u32 (lo=batch0, hi=batch1) -> 512B gather blocks.
__device__ unsigned g_xa[TT*NN*HH];   // 61.4 MB conv1 out, bf16 pair-packed [t][n][64]
__device__ unsigned g_ag[TT*NN*HH];   // 61.4 MB aggregation (layer2) [t][n][64]
__device__ float2   g_x9[(size_t)NN*NP];   // 20.5 MB conv3 out (fp32)
__device__ unsigned g_xp[(size_t)NN*NP];   // 10.2 MB input x (bf16 pair)
__device__ unsigned g_z9[(size_t)NN*NP];   // 10.2 MB x2@W3l (bf16 pair)
__device__ float2   g_r9[(size_t)NN*NP];   // 20.5 MB x2@W3r+b3 (fp32)
__device__ unsigned g_a9[(size_t)NN*NP];   // 10.2 MB layer-1 agg (bf16 pair)
__device__ int      g_rp[NN+1];
__device__ int      g_cnt[NN];
__device__ int      g_csrc[EE];
__device__ float    g_cw[EE];
__device__ float    g_cvec[32];

__device__ __forceinline__ float lo2f(unsigned u){ unsigned v=u<<16; float f; __builtin_memcpy(&f,&v,4); return f; }
__device__ __forceinline__ float hi2f(unsigned u){ unsigned v=u&0xffff0000u; float f; __builtin_memcpy(&f,&v,4); return f; }
__device__ __forceinline__ unsigned short f2us(float f){ bf h=__float2bfloat16(f); unsigned short u; __builtin_memcpy(&u,&h,2); return u; }
__device__ __forceinline__ unsigned pack2(float a0, float a1){ return (unsigned)f2us(a0) | ((unsigned)f2us(a1)<<16); }
__device__ __forceinline__ float elu(float x){ return x>0.f ? x : expm1f(x); }

// ---- CSR build -----------------------------------------------------------
__global__ void k_zero(){
  int i = blockIdx.x*256 + threadIdx.x;
  if(i < NN) g_cnt[i] = 0;
}
__global__ void k_count(const int* __restrict__ dst){
  int e = blockIdx.x*256 + threadIdx.x;
  if(e < EE) atomicAdd(&g_cnt[dst[e]], 1);
}
// scan + re-zero g_cnt + head precompute (all single-block work fused)
__global__ void k_scan(const float* __restrict__ encW, const float* __restrict__ encb,
                       const float* __restrict__ decW, const float* __restrict__ decb,
                       const float* __restrict__ te){
  __shared__ int part[256];
  __shared__ float c[19];
  const int CH = 79;
  int t = threadIdx.x;
  int base = t*CH;
  int s = 0;
  for(int i=0;i<CH;i++){ int idx=base+i; if(idx<NN) s += g_cnt[idx]; }
  part[t] = s; __syncthreads();
  for(int off=1; off<256; off<<=1){
    int v = (t>=off) ? part[t-off] : 0;
    __syncthreads();
    part[t] += v;
    __syncthreads();
  }
  int run = (t==0) ? 0 : part[t-1];
  for(int i=0;i<CH;i++){
    int idx=base+i;
    if(idx<NN){ run += g_cnt[idx]; g_rp[idx+1] = run; g_cnt[idx] = 0; }
  }
  if(t==0) g_rp[0] = 0;
  // ---- head ----
  if(t < 18){ float v=0.f; for(int j=0;j<64;j++) v += encW[t*64+j]*decW[j]; c[t]=v; }
  if(t == 18){ float v=decb[0]; for(int j=0;j<64;j++) v += encb[j]*decW[j]; c[18]=v; }
  __syncthreads();
  if(t < FF) g_cvec[t] = c[t];
  if(t < BB){ float v=c[18]; for(int k=0;k<FF;k++) v += te[t*FF+k]*c[9+k]; g_cvec[FF+t]=v; }
}
__global__ void k_fill(const int* __restrict__ dst, const int* __restrict__ src,
                       const float* __restrict__ ew){
  int e = blockIdx.x*256 + threadIdx.x;
  if(e >= EE) return;
  int d = dst[e];
  int pos = g_rp[d] + atomicAdd(&g_cnt[d], 1);
  g_csrc[pos] = src[e];
  g_cw[pos]   = ew[e];
}

// ---- pack input: xp[n][t*9+f] = bf16pair(x[b0], x[b1]) ------------------
__global__ void k_pack(const float* __restrict__ g){
  long i = (long)blockIdx.x*256 + threadIdx.x;
  if(i < (long)TT*NN*FF){
    int t = (int)(i / (NN*FF));
    int r = (int)(i - (long)t*NN*FF);
    int n = r / FF;
    int f = r - n*FF;
    g_xp[(size_t)n*NP + t*FF + f] = pack2(g[i], g[(long)TT*NN*FF + i]);
  }
}

// ---- agg1: owned-slot t-fused bf16 gather of x -> g_a9 (bf16 pair) ------
// 16-lane group covers a node's 512B block (2 uint4/lane = 8 u32 slots).
__global__ void k_agg1(){
  int tid = threadIdx.x;
  int lane = tid & 63;
  int grp  = lane >> 4;
  int sub  = lane & 15;
  int wid = (blockIdx.x*256+tid)>>6, nw = gridDim.x*4;
  for(int n=wid; n<NN; n+=nw){
    int r0=g_rp[n], r1=g_rp[n+1];
    float inv = 1.f/fmaxf((float)(r1-r0), 1.f);
    float acc[16];
    #pragma unroll
    for(int s=0;s<16;s++) acc[s]=0.f;
    for(int base=r0; base<r1; base+=64){
      int cnt = min(64, r1-base);
      int ms = 0; float mw = 0.f;
      if(lane < cnt){ ms = g_csrc[base+lane]; mw = g_cw[base+lane]; }
      for(int k=0;k<cnt;k+=4){
        int   sg = __shfl(ms, k+grp, 64);
        float wg = __shfl(mw, k+grp, 64);
        const uint4* p = reinterpret_cast<const uint4*>(g_xp + (size_t)sg*NP) + sub*2;
        uint4 v0=p[0], v1=p[1];
        acc[0] +=wg*lo2f(v0.x); acc[1] +=wg*hi2f(v0.x);
        acc[2] +=wg*lo2f(v0.y); acc[3] +=wg*hi2f(v0.y);
        acc[4] +=wg*lo2f(v0.z); acc[5] +=wg*hi2f(v0.z);
        acc[6] +=wg*lo2f(v0.w); acc[7] +=wg*hi2f(v0.w);
        acc[8] +=wg*lo2f(v1.x); acc[9] +=wg*hi2f(v1.x);
        acc[10]+=wg*lo2f(v1.y); acc[11]+=wg*hi2f(v1.y);
        acc[12]+=wg*lo2f(v1.z); acc[13]+=wg*hi2f(v1.z);
        acc[14]+=wg*lo2f(v1.w); acc[15]+=wg*hi2f(v1.w);
      }
    }
    #pragma unroll
    for(int s=0;s<16;s++){
      acc[s] += __shfl_xor(acc[s],16,64);
      acc[s] += __shfl_xor(acc[s],32,64);
    }
    if(grp == 0){
      uint4 w0, w1;
      w0.x = pack2(acc[0]*inv,  acc[1]*inv);
      w0.y = pack2(acc[2]*inv,  acc[3]*inv);
      w0.z = pack2(acc[4]*inv,  acc[5]*inv);
      w0.w = pack2(acc[6]*inv,  acc[7]*inv);
      w1.x = pack2(acc[8]*inv,  acc[9]*inv);
      w1.y = pack2(acc[10]*inv, acc[11]*inv);
      w1.z = pack2(acc[12]*inv, acc[13]*inv);
      w1.w = pack2(acc[14]*inv, acc[15]*inv);
      uint4* o = reinterpret_cast<uint4*>(g_a9 + (size_t)n*NP) + sub*2;
      o[0] = w0; o[1] = w1;
    }
  }
}

// ---- gemm1 (all t): ELU([AGG1|X]@[W1l;W1r]+b1) -> g_xa, K=18 pad 32 -----
__global__ __launch_bounds__(256) void k_gemm1(const float* __restrict__ Wl,
                                               const float* __restrict__ bias,
                                               const float* __restrict__ Wr){
  int t = blockIdx.y;
  __shared__ unsigned short sW[32*65];
  int tid = threadIdx.x;
  for(int i=tid; i<32*64; i+=256){
    int r = i >> 6, c = i & 63;
    float v = 0.f;
    if(r < FF)        v = Wl[(size_t)t*FF*HH + r*HH + c];
    else if(r < 2*FF) v = Wr[(size_t)t*FF*HH + (r-FF)*HH + c];
    sW[r*65+c] = f2us(v);
  }
  __syncthreads();
  int lane = tid & 63, wave = tid >> 6;
  int quad = lane >> 4, col = lane & 15;
  int base16 = blockIdx.x*64 + wave*16;
  if(base16 >= NN) return;
  size_t tb = (size_t)t*NN;
  int node = base16 + col;
  s8v A0, A1;
  #pragma unroll
  for(int j=0;j<8;j++){
    int k = quad*8 + j;
    unsigned u = 0;
    if(k < FF)        u = g_a9[(size_t)node*NP + t*FF + k];
    else if(k < 2*FF) u = g_xp[(size_t)node*NP + t*FF + (k-FF)];
    A0[j] = (short)(u & 0xffffu);
    A1[j] = (short)(u >> 16);
  }
  #pragma unroll
  for(int nt=0; nt<4; nt++){
    f4v c0 = {0.f,0.f,0.f,0.f}, c1 = {0.f,0.f,0.f,0.f};
    s8v B;
    #pragma unroll
    for(int j=0;j<8;j++)
      B[j] = (short)sW[(quad*8+j)*65 + nt*16+col];
    c0 = __builtin_amdgcn_mfma_f32_16x16x32_bf16(A0, B, c0, 0, 0, 0);
    c1 = __builtin_amdgcn_mfma_f32_16x16x32_bf16(A1, B, c1, 0, 0, 0);
    float bn = bias[t*HH + nt*16 + col];
    #pragma unroll
    for(int reg=0; reg<4; reg++){
      int nd = base16 + quad*4 + reg;
      g_xa[(tb+nd)*HH + nt*16 + col] = pack2(elu(c0[reg]+bn), elu(c1[reg]+bn));
    }
  }
}

// ---- agg (all t): 64-dim gather from g_xa; XCD-range partitioned --------
__global__ void k_agg_all(){
  const unsigned* __restrict__ src = g_xa;
  int tid = threadIdx.x;
  int lane = tid & 63;
  int grp  = lane >> 4;
  int sub  = lane & 15;
  const int TOT = TT*NN;
  const int SEG = TOT/8;               // 30000
  int xcd = blockIdx.x & 7;            // gfx950 round-robin block->XCD
  int lb  = blockIdx.x >> 3;
  int wid = (lb*256 + tid) >> 6;
  int nwx = (gridDim.x >> 3)*4;
  int lo = xcd*SEG, hi = lo + SEG;
  for(int idx=lo+wid; idx<hi; idx+=nwx){
    unsigned ut = (unsigned)idx / NN;
    int n = idx - (int)(ut*NN);
    size_t tb = (size_t)ut*NN;
    const unsigned* __restrict__ rowp = src + tb*HH + (sub<<2);
    int r0=g_rp[n], r1=g_rp[n+1];
    float inv = 1.f/fmaxf((float)(r1-r0), 1.f);
    float p0[4]={0.f,0.f,0.f,0.f}, p1[4]={0.f,0.f,0.f,0.f};
    for(int base=r0; base<r1; base+=64){
      int cnt = min(64, r1-base);
      int ms = 0; float mw = 0.f;
      if(lane < cnt){ ms = g_csrc[base+lane]; mw = g_cw[base+lane]; }
      for(int k=0;k<cnt;k+=4){
        int   sg = __shfl(ms, k+grp, 64);
        float wg = __shfl(mw, k+grp, 64);
        const uint4 v = *reinterpret_cast<const uint4*>(rowp + (size_t)sg*HH);
        p0[0]+=wg*lo2f(v.x); p1[0]+=wg*hi2f(v.x);
        p0[1]+=wg*lo2f(v.y); p1[1]+=wg*hi2f(v.y);
        p0[2]+=wg*lo2f(v.z); p1[2]+=wg*hi2f(v.z);
        p0[3]+=wg*lo2f(v.w); p1[3]+=wg*hi2f(v.w);
      }
    }
    #pragma unroll
    for(int q=0;q<4;q++){
      p0[q] += __shfl_xor(p0[q],16,64); p1[q] += __shfl_xor(p1[q],16,64);
      p0[q] += __shfl_xor(p0[q],32,64); p1[q] += __shfl_xor(p1[q],32,64);
    }
    if(lane < 16){
      uint4 o;
      o.x = pack2(p0[0]*inv, p1[0]*inv);
      o.y = pack2(p0[1]*inv, p1[1]*inv);
      o.z = pack2(p0[2]*inv, p1[2]*inv);
      o.w = pack2(p0[3]*inv, p1[3]*inv);
      *reinterpret_cast<uint4*>(g_ag + (tb + (size_t)n)*HH + (lane<<2)) = o;
    }
  }
}

// ---- gemm23 (all t): fused conv2 + projection. ---------------------------
__global__ __launch_bounds__(256) void k_gemm23(const float* __restrict__ W2l,
                                                const float* __restrict__ b2,
                                                const float* __restrict__ W2r,
                                                const float* __restrict__ W3l,
                                                const float* __restrict__ b3,
                                                const float* __restrict__ W3r){
  int t = blockIdx.y;
  __shared__ unsigned short sW2[128*65];  // 16.6 KB bf16
  __shared__ unsigned short sW3[128*10];  // 2.6 KB bf16
  __shared__ unsigned sXB[64*66];         // 16.9 KB packed bf16-pair xb tile
  int tid = threadIdx.x;
  for(int i=tid; i<64*64; i+=256){
    int r = i >> 6, c = i & 63;
    sW2[r*65+c]      = f2us(W2l[(size_t)t*4096 + i]);
    sW2[(r+64)*65+c] = f2us(W2r[(size_t)t*4096 + i]);
  }
  for(int i=tid; i<64*FF; i+=256){
    int r = i/FF, c = i - r*FF;
    sW3[r*10+c]      = f2us(W3l[(size_t)t*HH*FF + i]);
    sW3[(r+64)*10+c] = f2us(W3r[(size_t)t*HH*FF + i]);
  }
  __syncthreads();
  int lane = tid & 63, wave = tid >> 6;
  int quad = lane >> 4, col = lane & 15;
  int base16 = blockIdx.x*64 + wave*16;
  if(base16 >= NN) return;
  size_t tb = (size_t)t*NN;
  // ---- stage A: conv2 ----
  {
    int nodeA = base16 + col;
    s8v A0[4], A1[4];
    #pragma unroll
    for(int ks=0; ks<4; ks++){
      const unsigned* srcb = (ks < 2) ? g_ag : g_xa;
      int koff = (ks & 1)*32 + quad*8;
      const uint4 u = *reinterpret_cast<const uint4*>(srcb + (tb+nodeA)*HH + koff);
      const uint4 v = *reinterpret_cast<const uint4*>(srcb + (tb+nodeA)*HH + koff + 4);
      unsigned uu[8] = {u.x,u.y,u.z,u.w,v.x,v.y,v.z,v.w};
      #pragma unroll
      for(int j=0;j<8;j++){
        A0[ks][j] = (short)(uu[j] & 0xffffu);
        A1[ks][j] = (short)(uu[j] >> 16);
      }
    }
    #pragma unroll
    for(int nt=0; nt<4; nt++){
      f4v c0 = {0.f,0.f,0.f,0.f}, c1 = {0.f,0.f,0.f,0.f};
      #pragma unroll
      for(int ks=0; ks<4; ks++){
        s8v B;
        #pragma unroll
        for(int j=0;j<8;j++)
          B[j] = (short)sW2[(ks*32+quad*8+j)*65 + nt*16+col];
        c0 = __builtin_amdgcn_mfma_f32_16x16x32_bf16(A0[ks], B, c0, 0, 0, 0);
        c1 = __builtin_amdgcn_mfma_f32_16x16x32_bf16(A1[ks], B, c1, 0, 0, 0);
      }
      float bn = b2[t*HH + nt*16 + col];
      #pragma unroll
      for(int reg=0; reg<4; reg++){
        int nl = wave*16 + quad*4 + reg;          // wave-private rows
        sXB[nl*66 + nt*16 + col] = pack2(elu(c0[reg]+bn), elu(c1[reg]+bn));
      }
    }
  }
  // wave-private tile: each wave reads only rows it wrote; no barrier needed.
  // ---- stage B: project to 9-dim ----
  {
    f4v z0={0.f,0.f,0.f,0.f}, z1={0.f,0.f,0.f,0.f};
    f4v r0={0.f,0.f,0.f,0.f}, r1={0.f,0.f,0.f,0.f};
    int nlA = wave*16 + col;
    #pragma unroll
    for(int ks=0; ks<2; ks++){
      int koff = ks*32 + quad*8;
      s8v A0, A1, Bl, Br;
      #pragma unroll
      for(int j=0;j<8;j++){
        unsigned u = sXB[nlA*66 + koff + j];
        A0[j] = (short)(u & 0xffffu);
        A1[j] = (short)(u >> 16);
        int row = ks*32 + quad*8 + j;
        Bl[j] = (col < FF) ? (short)sW3[row*10 + col]      : (short)0;
        Br[j] = (col < FF) ? (short)sW3[(row+64)*10 + col] : (short)0;
      }
      z0 = __builtin_amdgcn_mfma_f32_16x16x32_bf16(A0, Bl, z0, 0, 0, 0);
      z1 = __builtin_amdgcn_mfma_f32_16x16x32_bf16(A1, Bl, z1, 0, 0, 0);
      r0 = __builtin_amdgcn_mfma_f32_16x16x32_bf16(A0, Br, r0, 0, 0, 0);
      r1 = __builtin_amdgcn_mfma_f32_16x16x32_bf16(A1, Br, r1, 0, 0, 0);
    }
    if(col < FF){
      float bn = b3[t*FF + col];
      #pragma unroll
      for(int reg=0; reg<4; reg++){
        int node = base16 + quad*4 + reg;
        g_z9[(size_t)node*NP + t*FF + col] = pack2(z0[reg], z1[reg]);
        float2 orr; orr.x = r0[reg]+bn; orr.y = r1[reg]+bn;
        g_r9[(size_t)node*NP + t*FF + col] = orr;
      }
    }
  }
}

// ---- agg9f: owned-slot t-fused bf16 gather of Z, + R, ELU -> g_x9 -------
__global__ void k_agg9f(){
  int tid = threadIdx.x;
  int lane = tid & 63;
  int grp  = lane >> 4;
  int sub  = lane & 15;
  int wid = (blockIdx.x*256+tid)>>6, nw = gridDim.x*4;
  for(int n=wid; n<NN; n+=nw){
    int r0=g_rp[n], r1=g_rp[n+1];
    float inv = 1.f/fmaxf((float)(r1-r0), 1.f);
    float acc[16];
    #pragma unroll
    for(int s=0;s<16;s++) acc[s]=0.f;
    for(int base=r0; base<r1; base+=64){
      int cnt = min(64, r1-base);
      int ms = 0; float mw = 0.f;
      if(lane < cnt){ ms = g_csrc[base+lane]; mw = g_cw[base+lane]; }
      for(int k=0;k<cnt;k+=4){
        int   sg = __shfl(ms, k+grp, 64);
        float wg = __shfl(mw, k+grp, 64);
        const uint4* p = reinterpret_cast<const uint4*>(g_z9 + (size_t)sg*NP) + sub*2;
        uint4 v0=p[0], v1=p[1];
        acc[0] +=wg*lo2f(v0.x); acc[1] +=wg*hi2f(v0.x);
        acc[2] +=wg*lo2f(v0.y); acc[3] +=wg*hi2f(v0.y);
        acc[4] +=wg*lo2f(v0.z); acc[5] +=wg*hi2f(v0.z);
        acc[6] +=wg*lo2f(v0.w); acc[7] +=wg*hi2f(v0.w);
        acc[8] +=wg*lo2f(v1.x); acc[9] +=wg*hi2f(v1.x);
        acc[10]+=wg*lo2f(v1.y); acc[11]+=wg*hi2f(v1.y);
        acc[12]+=wg*lo2f(v1.z); acc[13]+=wg*hi2f(v1.z);
        acc[14]+=wg*lo2f(v1.w); acc[15]+=wg*hi2f(v1.w);
      }
    }
    #pragma unroll
    for(int s=0;s<16;s++){
      acc[s] += __shfl_xor(acc[s],16,64);
      acc[s] += __shfl_xor(acc[s],32,64);
    }
    if(grp == 0){
      const float4* rp4 = reinterpret_cast<const float4*>(g_r9 + (size_t)n*NP) + sub*4;
      float4* o = reinterpret_cast<float4*>(g_x9 + (size_t)n*NP) + sub*4;
      #pragma unroll
      for(int q=0;q<4;q++){
        float4 r = rp4[q];
        float4 w;
        w.x = elu(acc[q*4+0]*inv + r.x);
        w.y = elu(acc[q*4+1]*inv + r.y);
        w.z = elu(acc[q*4+2]*inv + r.z);
        w.w = elu(acc[q*4+3]*inv + r.w);
        o[q] = w;
      }
    }
  }
}

// ---- k_gru_fused: feature-parallel GRU, gix fused in-register -----------
__global__ __launch_bounds__(256) void k_gru_fused(const float* __restrict__ g,
                          const float* __restrict__ Wih, const float* __restrict__ Whh,
                          const float* __restrict__ bih, const float* __restrict__ bhh,
                          float* __restrict__ out){
  __shared__ float sWih[TT*FF*27];   // 11664 B
  __shared__ float sWhh[TT*FF*27];   // 11664 B
  __shared__ float sbih[TT*27], sbhh[TT*27];
  int tid = threadIdx.x;
  for(int i=tid;i<TT*FF*27;i+=256){ sWih[i]=Wih[i]; sWhh[i]=Whh[i]; }
  for(int i=tid;i<TT*27;i+=256){ sbih[i]=bih[i]; sbhh[i]=bhh[i]; }
  __syncthreads();
  int lane = tid & 63;
  int wv   = tid >> 6;
  int p    = lane / 9;               // 0..6 live, p==7 is the idle lane 63
  int f    = lane - p*9;
  int gbase = p*9;
  int id = (blockIdx.x*4 + wv)*7 + p;
  bool valid = (p < 7) && (id < BB*NN);
  int b = 0, n = 0;
  if(valid){ b = (id >= NN) ? 1 : 0; n = id - b*NN; }
  float c9[FF];
  #pragma unroll
  for(int i=0;i<FF;i++) c9[i] = g_cvec[i];
  float cb = g_cvec[FF+b];
  float h = 0.f;
  float hs[FF];
  #pragma unroll
  for(int i=0;i<FF;i++) hs[i] = 0.f;
  for(int t=0;t<TT;t++){
    float x = 0.f;
    if(valid){
      float2 xf = g_x9[(size_t)n*NP + t*FF + f];
      x = b ? xf.y : xf.x;
    }
    float xs[FF];
    #pragma unroll
    for(int i=0;i<FF;i++) xs[i] = __shfl(x, gbase+i, 64);
    const float* wi = &sWih[t*FF*27];
    const float* wh = &sWhh[t*FF*27];
    float gir = sbih[t*27+f], giz = sbih[t*27+9+f], gin = sbih[t*27+18+f];
    float ghr = sbhh[t*27+f], ghz = sbhh[t*27+9+f], ghn = sbhh[t*27+18+f];
    #pragma unroll
    for(int i=0;i<FF;i++){
      float xi = xs[i], hi = hs[i];
      gir += xi*wi[i*27+f];    giz += xi*wi[i*27+9+f];    gin += xi*wi[i*27+18+f];
      ghr += hi*wh[i*27+f];    ghz += hi*wh[i*27+9+f];    ghn += hi*wh[i*27+18+f];
    }
    float r = 1.f/(1.f+__expf(-(gir+ghr)));
    float z = 1.f/(1.f+__expf(-(giz+ghz)));
    float nv = tanhf(gin + r*ghn);
    h = (1.f-z)*nv + z*h;
    #pragma unroll
    for(int i=0;i<FF;i++) hs[i] = __shfl(h, gbase+i, 64);
    if(valid && f == 0){
      float acc = cb;
      #pragma unroll
      for(int i=0;i<FF;i++) acc += hs[i]*c9[i];
      size_t gidx = (size_t)(b*TT+t)*NN + n;
      float m = (g[gidx*FF] != 0.f) ? 1.f : 0.f;
      out[gidx] = acc*m;
    }
  }
}

extern "C" void kernel_launch(void* const* d_in, const int* in_sizes, int n_in,
                              void* d_out, int out_size, void* d_ws, size_t ws_size,
                              hipStream_t stream){
  const float* g    = (const float*)d_in[0];
  const float* te   = (const float*)d_in[1];
  const float* ew   = (const float*)d_in[3];
  const int* esrc = (const int*)d_in[4];
  const int* edst = (const int*)d_in[5];
  const float* W1l=(const float*)d_in[6];  const float* b1 =(const float*)d_in[7];  const float* W1r=(const float*)d_in[8];
  const float* W2l=(const float*)d_in[9];  const float* b2 =(const float*)d_in[10]; const float* W2r=(const float*)d_in[11];
  const float* W3l=(const float*)d_in[12]; const float* b3 =(const float*)d_in[13]; const float* W3r=(const float*)d_in[14];
  const float* Wih=(const float*)d_in[15]; const float* Whh=(const float*)d_in[16];
  const float* bih=(const float*)d_in[17]; const float* bhh=(const float*)d_in[18];
  const float* encW=(const float*)d_in[19]; const float* encb=(const float*)d_in[20];
  const float* decW=(const float*)d_in[21]; const float* decb=(const float*)d_in[22];
  float* out = (float*)d_out;

  k_zero <<<(NN+255)/256, 256, 0, stream>>>();
  k_count<<<(EE+255)/256, 256, 0, stream>>>(edst);
  k_scan <<<1, 256, 0, stream>>>(encW, encb, decW, decb, te);
  k_fill <<<(EE+255)/256, 256, 0, stream>>>(edst, esrc, ew);
  k_pack <<<((long)TT*NN*FF+255)/256, 256, 0, stream>>>(g);

  dim3 ggm((NN+63)/64, TT);
  k_agg1<<<2048, 256, 0, stream>>>();
  k_gemm1<<<ggm, 256, 0, stream>>>(W1l, b1, W1r);
  k_agg_all<<<2048, 256, 0, stream>>>();
  k_gemm23<<<ggm, 256, 0, stream>>>(W2l, b2, W2r, W3l, b3, W3r);
  k_agg9f<<<2048, 256, 0, stream>>>();
  // pairs = BB*NN; 28 pairs per 256-thread block (4 waves x 7)
  int nblk = (BB*NN + 27) / 28;
  k_gru_fused<<<nblk, 256, 0, stream>>>(g, Wih, Whh, bih, bhh, out);
}

// Round 17
// 468.981 us; speedup vs baseline: 1.0306x; 1.0119x over previous
//
#include <hip/hip_runtime.h>
#include <hip/hip_bf16.h>

#define BB 2
#define TT 12
#define NN 20000
#define FF 9
#define HH 64
#define EE 200000
#define NP 128   // padded slots per node for 9-dim tensors (12*9=108 used)

typedef __hip_bfloat16 bf;
typedef __attribute__((ext_vector_type(8))) short s8v;   // 8 bf16 (4 VGPRs)
typedef __attribute__((ext_vector_type(4))) float f4v;

// ---- big buffers: all-timestep activations (static device globals) -------
// 9-dim tensors are [n][NP] slots (slot = t*9+f, pad 108..127 stays zero).
// xp/a9/z9 are bf16 PAIR-PACKED u32 (lo=batch0, hi=batch1) -> 512B gather blocks.
// g_cme: packed edge meta = (src<<16) | bf16(weight)  (src < 20000 < 2^15)
__device__ unsigned g_xa[TT*NN*HH];   // 61.4 MB conv1 out, bf16 pair-packed [t][n][64]
__device__ unsigned g_ag[TT*NN*HH];   // 61.4 MB aggregation (layer2) [t][n][64]
__device__ float2   g_x9[(size_t)NN*NP];   // 20.5 MB conv3 out (fp32)
__device__ unsigned g_xp[(size_t)NN*NP];   // 10.2 MB input x (bf16 pair)
__device__ unsigned g_z9[(size_t)NN*NP];   // 10.2 MB x2@W3l (bf16 pair)
__device__ float2   g_r9[(size_t)NN*NP];   // 20.5 MB x2@W3r+b3 (fp32)
__device__ unsigned g_a9[(size_t)NN*NP];   // 10.2 MB layer-1 agg (bf16 pair)
__device__ int      g_rp[NN+1];
__device__ int      g_cnt[NN];
__device__ unsigned g_cme[EE];
__device__ float    g_cvec[32];

__device__ __forceinline__ float lo2f(unsigned u){ unsigned v=u<<16; float f; __builtin_memcpy(&f,&v,4); return f; }
__device__ __forceinline__ float hi2f(unsigned u){ unsigned v=u&0xffff0000u; float f; __builtin_memcpy(&f,&v,4); return f; }
__device__ __forceinline__ unsigned short f2us(float f){ bf h=__float2bfloat16(f); unsigned short u; __builtin_memcpy(&u,&h,2); return u; }
__device__ __forceinline__ unsigned pack2(float a0, float a1){ return (unsigned)f2us(a0) | ((unsigned)f2us(a1)<<16); }
__device__ __forceinline__ float elu(float x){ return x>0.f ? x : expm1f(x); }

// ---- CSR build -----------------------------------------------------------
__global__ void k_zero(){
  int i = blockIdx.x*256 + threadIdx.x;
  if(i < NN) g_cnt[i] = 0;
}
// merged: degree count (atomics) + input pack (independent pre-CSR work)
__global__ void k_count_pack(const int* __restrict__ dst, const float* __restrict__ g){
  long i = (long)blockIdx.x*256 + threadIdx.x;
  if(i < EE) atomicAdd(&g_cnt[dst[i]], 1);
  if(i < (long)TT*NN*FF){
    int t = (int)(i / (NN*FF));
    int r = (int)(i - (long)t*NN*FF);
    int n = r / FF;
    int f = r - n*FF;
    g_xp[(size_t)n*NP + t*FF + f] = pack2(g[i], g[(long)TT*NN*FF + i]);
  }
}
// scan + re-zero g_cnt + head precompute (all single-block work fused)
__global__ void k_scan(const float* __restrict__ encW, const float* __restrict__ encb,
                       const float* __restrict__ decW, const float* __restrict__ decb,
                       const float* __restrict__ te){
  __shared__ int part[256];
  __shared__ float c[19];
  const int CH = 79;
  int t = threadIdx.x;
  int base = t*CH;
  int s = 0;
  for(int i=0;i<CH;i++){ int idx=base+i; if(idx<NN) s += g_cnt[idx]; }
  part[t] = s; __syncthreads();
  for(int off=1; off<256; off<<=1){
    int v = (t>=off) ? part[t-off] : 0;
    __syncthreads();
    part[t] += v;
    __syncthreads();
  }
  int run = (t==0) ? 0 : part[t-1];
  for(int i=0;i<CH;i++){
    int idx=base+i;
    if(idx<NN){ run += g_cnt[idx]; g_rp[idx+1] = run; g_cnt[idx] = 0; }
  }
  if(t==0) g_rp[0] = 0;
  // ---- head ----
  if(t < 18){ float v=0.f; for(int j=0;j<64;j++) v += encW[t*64+j]*decW[j]; c[t]=v; }
  if(t == 18){ float v=decb[0]; for(int j=0;j<64;j++) v += encb[j]*decW[j]; c[18]=v; }
  __syncthreads();
  if(t < FF) g_cvec[t] = c[t];
  if(t < BB){ float v=c[18]; for(int k=0;k<FF;k++) v += te[t*FF+k]*c[9+k]; g_cvec[FF+t]=v; }
}
__global__ void k_fill(const int* __restrict__ dst, const int* __restrict__ src,
                       const float* __restrict__ ew){
  int e = blockIdx.x*256 + threadIdx.x;
  if(e >= EE) return;
  int d = dst[e];
  int pos = g_rp[d] + atomicAdd(&g_cnt[d], 1);
  g_cme[pos] = ((unsigned)src[e] << 16) | (unsigned)f2us(ew[e]);
}

// ---- agg1: owned-slot t-fused bf16 gather of x -> g_a9 (bf16 pair) ------
// 16-lane group covers a node's 512B block (2 uint4/lane = 8 u32 slots).
__global__ void k_agg1(){
  int tid = threadIdx.x;
  int lane = tid & 63;
  int grp  = lane >> 4;
  int sub  = lane & 15;
  int wid = (blockIdx.x*256+tid)>>6, nw = gridDim.x*4;
  for(int n=wid; n<NN; n+=nw){
    int r0=g_rp[n], r1=g_rp[n+1];
    float inv = 1.f/fmaxf((float)(r1-r0), 1.f);
    float acc[16];
    #pragma unroll
    for(int s=0;s<16;s++) acc[s]=0.f;
    for(int base=r0; base<r1; base+=64){
      int cnt = min(64, r1-base);
      int mm = 0;
      if(lane < cnt) mm = (int)g_cme[base+lane];
      for(int k=0;k<cnt;k+=4){
        unsigned um = (unsigned)__shfl(mm, k+grp, 64);
        int   sg = (int)(um >> 16);
        float wg = lo2f(um);
        const uint4* p = reinterpret_cast<const uint4*>(g_xp + (size_t)sg*NP) + sub*2;
        uint4 v0=p[0], v1=p[1];
        acc[0] +=wg*lo2f(v0.x); acc[1] +=wg*hi2f(v0.x);
        acc[2] +=wg*lo2f(v0.y); acc[3] +=wg*hi2f(v0.y);
        acc[4] +=wg*lo2f(v0.z); acc[5] +=wg*hi2f(v0.z);
        acc[6] +=wg*lo2f(v0.w); acc[7] +=wg*hi2f(v0.w);
        acc[8] +=wg*lo2f(v1.x); acc[9] +=wg*hi2f(v1.x);
        acc[10]+=wg*lo2f(v1.y); acc[11]+=wg*hi2f(v1.y);
        acc[12]+=wg*lo2f(v1.z); acc[13]+=wg*hi2f(v1.z);
        acc[14]+=wg*lo2f(v1.w); acc[15]+=wg*hi2f(v1.w);
      }
    }
    #pragma unroll
    for(int s=0;s<16;s++){
      acc[s] += __shfl_xor(acc[s],16,64);
      acc[s] += __shfl_xor(acc[s],32,64);
    }
    if(grp == 0){
      uint4 w0, w1;
      w0.x = pack2(acc[0]*inv,  acc[1]*inv);
      w0.y = pack2(acc[2]*inv,  acc[3]*inv);
      w0.z = pack2(acc[4]*inv,  acc[5]*inv);
      w0.w = pack2(acc[6]*inv,  acc[7]*inv);
      w1.x = pack2(acc[8]*inv,  acc[9]*inv);
      w1.y = pack2(acc[10]*inv, acc[11]*inv);
      w1.z = pack2(acc[12]*inv, acc[13]*inv);
      w1.w = pack2(acc[14]*inv, acc[15]*inv);
      uint4* o = reinterpret_cast<uint4*>(g_a9 + (size_t)n*NP) + sub*2;
      o[0] = w0; o[1] = w1;
    }
  }
}

// ---- gemm1 (all t): ELU([AGG1|X]@[W1l;W1r]+b1) -> g_xa, K=18 pad 32 -----
__global__ __launch_bounds__(256) void k_gemm1(const float* __restrict__ Wl,
                                               const float* __restrict__ bias,
                                               const float* __restrict__ Wr){
  int t = blockIdx.y;
  __shared__ unsigned short sW[32*65];
  int tid = threadIdx.x;
  for(int i=tid; i<32*64; i+=256){
    int r = i >> 6, c = i & 63;
    float v = 0.f;
    if(r < FF)        v = Wl[(size_t)t*FF*HH + r*HH + c];
    else if(r < 2*FF) v = Wr[(size_t)t*FF*HH + (r-FF)*HH + c];
    sW[r*65+c] = f2us(v);
  }
  __syncthreads();
  int lane = tid & 63, wave = tid >> 6;
  int quad = lane >> 4, col = lane & 15;
  int base16 = blockIdx.x*64 + wave*16;
  if(base16 >= NN) return;
  size_t tb = (size_t)t*NN;
  int node = base16 + col;
  s8v A0, A1;
  #pragma unroll
  for(int j=0;j<8;j++){
    int k = quad*8 + j;
    unsigned u = 0;
    if(k < FF)        u = g_a9[(size_t)node*NP + t*FF + k];
    else if(k < 2*FF) u = g_xp[(size_t)node*NP + t*FF + (k-FF)];
    A0[j] = (short)(u & 0xffffu);
    A1[j] = (short)(u >> 16);
  }
  #pragma unroll
  for(int nt=0; nt<4; nt++){
    f4v c0 = {0.f,0.f,0.f,0.f}, c1 = {0.f,0.f,0.f,0.f};
    s8v B;
    #pragma unroll
    for(int j=0;j<8;j++)
      B[j] = (short)sW[(quad*8+j)*65 + nt*16+col];
    c0 = __builtin_amdgcn_mfma_f32_16x16x32_bf16(A0, B, c0, 0, 0, 0);
    c1 = __builtin_amdgcn_mfma_f32_16x16x32_bf16(A1, B, c1, 0, 0, 0);
    float bn = bias[t*HH + nt*16 + col];
    #pragma unroll
    for(int reg=0; reg<4; reg++){
      int nd = base16 + quad*4 + reg;
      g_xa[(tb+nd)*HH + nt*16 + col] = pack2(elu(c0[reg]+bn), elu(c1[reg]+bn));
    }
  }
}

// ---- agg (all t): 64-dim gather from g_xa; XCD-range partitioned --------
__global__ void k_agg_all(){
  const unsigned* __restrict__ src = g_xa;
  int tid = threadIdx.x;
  int lane = tid & 63;
  int grp  = lane >> 4;
  int sub  = lane & 15;
  const int TOT = TT*NN;
  const int SEG = TOT/8;               // 30000
  int xcd = blockIdx.x & 7;            // gfx950 round-robin block->XCD
  int lb  = blockIdx.x >> 3;
  int wid = (lb*256 + tid) >> 6;
  int nwx = (gridDim.x >> 3)*4;
  int lo = xcd*SEG, hi = lo + SEG;
  for(int idx=lo+wid; idx<hi; idx+=nwx){
    unsigned ut = (unsigned)idx / NN;
    int n = idx - (int)(ut*NN);
    size_t tb = (size_t)ut*NN;
    const unsigned* __restrict__ rowp = src + tb*HH + (sub<<2);
    int r0=g_rp[n], r1=g_rp[n+1];
    float inv = 1.f/fmaxf((float)(r1-r0), 1.f);
    float p0[4]={0.f,0.f,0.f,0.f}, p1[4]={0.f,0.f,0.f,0.f};
    for(int base=r0; base<r1; base+=64){
      int cnt = min(64, r1-base);
      int mm = 0;
      if(lane < cnt) mm = (int)g_cme[base+lane];
      for(int k=0;k<cnt;k+=4){
        unsigned um = (unsigned)__shfl(mm, k+grp, 64);
        int   sg = (int)(um >> 16);
        float wg = lo2f(um);
        const uint4 v = *reinterpret_cast<const uint4*>(rowp + (size_t)sg*HH);
        p0[0]+=wg*lo2f(v.x); p1[0]+=wg*hi2f(v.x);
        p0[1]+=wg*lo2f(v.y); p1[1]+=wg*hi2f(v.y);
        p0[2]+=wg*lo2f(v.z); p1[2]+=wg*hi2f(v.z);
        p0[3]+=wg*lo2f(v.w); p1[3]+=wg*hi2f(v.w);
      }
    }
    #pragma unroll
    for(int q=0;q<4;q++){
      p0[q] += __shfl_xor(p0[q],16,64); p1[q] += __shfl_xor(p1[q],16,64);
      p0[q] += __shfl_xor(p0[q],32,64); p1[q] += __shfl_xor(p1[q],32,64);
    }
    if(lane < 16){
      uint4 o;
      o.x = pack2(p0[0]*inv, p1[0]*inv);
      o.y = pack2(p0[1]*inv, p1[1]*inv);
      o.z = pack2(p0[2]*inv, p1[2]*inv);
      o.w = pack2(p0[3]*inv, p1[3]*inv);
      *reinterpret_cast<uint4*>(g_ag + (tb + (size_t)n)*HH + (lane<<2)) = o;
    }
  }
}

// ---- gemm23 (all t): fused conv2 + projection. ---------------------------
__global__ __launch_bounds__(256) void k_gemm23(const float* __restrict__ W2l,
                                                const float* __restrict__ b2,
                                                const float* __restrict__ W2r,
                                                const float* __restrict__ W3l,
                                                const float* __restrict__ b3,
                                                const float* __restrict__ W3r){
  int t = blockIdx.y;
  __shared__ unsigned short sW2[128*65];  // 16.6 KB bf16
  __shared__ unsigned short sW3[128*10];  // 2.6 KB bf16
  __shared__ unsigned sXB[64*66];         // 16.9 KB packed bf16-pair xb tile
  int tid = threadIdx.x;
  for(int i=tid; i<64*64; i+=256){
    int r = i >> 6, c = i & 63;
    sW2[r*65+c]      = f2us(W2l[(size_t)t*4096 + i]);
    sW2[(r+64)*65+c] = f2us(W2r[(size_t)t*4096 + i]);
  }
  for(int i=tid; i<64*FF; i+=256){
    int r = i/FF, c = i - r*FF;
    sW3[r*10+c]      = f2us(W3l[(size_t)t*HH*FF + i]);
    sW3[(r+64)*10+c] = f2us(W3r[(size_t)t*HH*FF + i]);
  }
  __syncthreads();
  int lane = tid & 63, wave = tid >> 6;
  int quad = lane >> 4, col = lane & 15;
  int base16 = blockIdx.x*64 + wave*16;
  if(base16 >= NN) return;
  size_t tb = (size_t)t*NN;
  // ---- stage A: conv2 ----
  {
    int nodeA = base16 + col;
    s8v A0[4], A1[4];
    #pragma unroll
    for(int ks=0; ks<4; ks++){
      const unsigned* srcb = (ks < 2) ? g_ag : g_xa;
      int koff = (ks & 1)*32 + quad*8;
      const uint4 u = *reinterpret_cast<const uint4*>(srcb + (tb+nodeA)*HH + koff);
      const uint4 v = *reinterpret_cast<const uint4*>(srcb + (tb+nodeA)*HH + koff + 4);
      unsigned uu[8] = {u.x,u.y,u.z,u.w,v.x,v.y,v.z,v.w};
      #pragma unroll
      for(int j=0;j<8;j++){
        A0[ks][j] = (short)(uu[j] & 0xffffu);
        A1[ks][j] = (short)(uu[j] >> 16);
      }
    }
    #pragma unroll
    for(int nt=0; nt<4; nt++){
      f4v c0 = {0.f,0.f,0.f,0.f}, c1 = {0.f,0.f,0.f,0.f};
      #pragma unroll
      for(int ks=0; ks<4; ks++){
        s8v B;
        #pragma unroll
        for(int j=0;j<8;j++)
          B[j] = (short)sW2[(ks*32+quad*8+j)*65 + nt*16+col];
        c0 = __builtin_amdgcn_mfma_f32_16x16x32_bf16(A0[ks], B, c0, 0, 0, 0);
        c1 = __builtin_amdgcn_mfma_f32_16x16x32_bf16(A1[ks], B, c1, 0, 0, 0);
      }
      float bn = b2[t*HH + nt*16 + col];
      #pragma unroll
      for(int reg=0; reg<4; reg++){
        int nl = wave*16 + quad*4 + reg;          // wave-private rows
        sXB[nl*66 + nt*16 + col] = pack2(elu(c0[reg]+bn), elu(c1[reg]+bn));
      }
    }
  }
  // wave-private tile: each wave reads only rows it wrote; no barrier needed.
  // ---- stage B: project to 9-dim ----
  {
    f4v z0={0.f,0.f,0.f,0.f}, z1={0.f,0.f,0.f,0.f};
    f4v r0={0.f,0.f,0.f,0.f}, r1={0.f,0.f,0.f,0.f};
    int nlA = wave*16 + col;
    #pragma unroll
    for(int ks=0; ks<2; ks++){
      int koff = ks*32 + quad*8;
      s8v A0, A1, Bl, Br;
      #pragma unroll
      for(int j=0;j<8;j++){
        unsigned u = sXB[nlA*66 + koff + j];
        A0[j] = (short)(u & 0xffffu);
        A1[j] = (short)(u >> 16);
        int row = ks*32 + quad*8 + j;
        Bl[j] = (col < FF) ? (short)sW3[row*10 + col]      : (short)0;
        Br[j] = (col < FF) ? (short)sW3[(row+64)*10 + col] : (short)0;
      }
      z0 = __builtin_amdgcn_mfma_f32_16x16x32_bf16(A0, Bl, z0, 0, 0, 0);
      z1 = __builtin_amdgcn_mfma_f32_16x16x32_bf16(A1, Bl, z1, 0, 0, 0);
      r0 = __builtin_amdgcn_mfma_f32_16x16x32_bf16(A0, Br, r0, 0, 0, 0);
      r1 = __builtin_amdgcn_mfma_f32_16x16x32_bf16(A1, Br, r1, 0, 0, 0);
    }
    if(col < FF){
      float bn = b3[t*FF + col];
      #pragma unroll
      for(int reg=0; reg<4; reg++){
        int node = base16 + quad*4 + reg;
        g_z9[(size_t)node*NP + t*FF + col] = pack2(z0[reg], z1[reg]);
        float2 orr; orr.x = r0[reg]+bn; orr.y = r1[reg]+bn;
        g_r9[(size_t)node*NP + t*FF + col] = orr;
      }
    }
  }
}

// ---- agg9f: owned-slot t-fused bf16 gather of Z, + R, ELU -> g_x9 -------
__global__ void k_agg9f(){
  int tid = threadIdx.x;
  int lane = tid & 63;
  int grp  = lane >> 4;
  int sub  = lane & 15;
  int wid = (blockIdx.x*256+tid)>>6, nw = gridDim.x*4;
  for(int n=wid; n<NN; n+=nw){
    int r0=g_rp[n], r1=g_rp[n+1];
    float inv = 1.f/fmaxf((float)(r1-r0), 1.f);
    float acc[16];
    #pragma unroll
    for(int s=0;s<16;s++) acc[s]=0.f;
    for(int base=r0; base<r1; base+=64){
      int cnt = min(64, r1-base);
      int mm = 0;
      if(lane < cnt) mm = (int)g_cme[base+lane];
      for(int k=0;k<cnt;k+=4){
        unsigned um = (unsigned)__shfl(mm, k+grp, 64);
        int   sg = (int)(um >> 16);
        float wg = lo2f(um);
        const uint4* p = reinterpret_cast<const uint4*>(g_z9 + (size_t)sg*NP) + sub*2;
        uint4 v0=p[0], v1=p[1];
        acc[0] +=wg*lo2f(v0.x); acc[1] +=wg*hi2f(v0.x);
        acc[2] +=wg*lo2f(v0.y); acc[3] +=wg*hi2f(v0.y);
        acc[4] +=wg*lo2f(v0.z); acc[5] +=wg*hi2f(v0.z);
        acc[6] +=wg*lo2f(v0.w); acc[7] +=wg*hi2f(v0.w);
        acc[8] +=wg*lo2f(v1.x); acc[9] +=wg*hi2f(v1.x);
        acc[10]+=wg*lo2f(v1.y); acc[11]+=wg*hi2f(v1.y);
        acc[12]+=wg*lo2f(v1.z); acc[13]+=wg*hi2f(v1.z);
        acc[14]+=wg*lo2f(v1.w); acc[15]+=wg*hi2f(v1.w);
      }
    }
    #pragma unroll
    for(int s=0;s<16;s++){
      acc[s] += __shfl_xor(acc[s],16,64);
      acc[s] += __shfl_xor(acc[s],32,64);
    }
    if(grp == 0){
      const float4* rp4 = reinterpret_cast<const float4*>(g_r9 + (size_t)n*NP) + sub*4;
      float4* o = reinterpret_cast<float4*>(g_x9 + (size_t)n*NP) + sub*4;
      #pragma unroll
      for(int q=0;q<4;q++){
        float4 r = rp4[q];
        float4 w;
        w.x = elu(acc[q*4+0]*inv + r.x);
        w.y = elu(acc[q*4+1]*inv + r.y);
        w.z = elu(acc[q*4+2]*inv + r.z);
        w.w = elu(acc[q*4+3]*inv + r.w);
        o[q] = w;
      }
    }
  }
}

// ---- k_gru_fused: feature-parallel GRU, gix fused in-register -----------
__global__ __launch_bounds__(256) void k_gru_fused(const float* __restrict__ g,
                          const float* __restrict__ Wih, const float* __restrict__ Whh,
                          const float* __restrict__ bih, const float* __restrict__ bhh,
                          float* __restrict__ out){
  __shared__ float sWih[TT*FF*27];   // 11664 B
  __shared__ float sWhh[TT*FF*27];   // 11664 B
  __shared__ float sbih[TT*27], sbhh[TT*27];
  int tid = threadIdx.x;
  for(int i=tid;i<TT*FF*27;i+=256){ sWih[i]=Wih[i]; sWhh[i]=Whh[i]; }
  for(int i=tid;i<TT*27;i+=256){ sbih[i]=bih[i]; sbhh[i]=bhh[i]; }
  __syncthreads();
  int lane = tid & 63;
  int wv   = tid >> 6;
  int p    = lane / 9;               // 0..6 live, p==7 is the idle lane 63
  int f    = lane - p*9;
  int gbase = p*9;
  int id = (blockIdx.x*4 + wv)*7 + p;
  bool valid = (p < 7) && (id < BB*NN);
  int b = 0, n = 0;
  if(valid){ b = (id >= NN) ? 1 : 0; n = id - b*NN; }
  float c9[FF];
  #pragma unroll
  for(int i=0;i<FF;i++) c9[i] = g_cvec[i];
  float cb = g_cvec[FF+b];
  float h = 0.f;
  float hs[FF];
  #pragma unroll
  for(int i=0;i<FF;i++) hs[i] = 0.f;
  for(int t=0;t<TT;t++){
    float x = 0.f;
    if(valid){
      float2 xf = g_x9[(size_t)n*NP + t*FF + f];
      x = b ? xf.y : xf.x;
    }
    float xs[FF];
    #pragma unroll
    for(int i=0;i<FF;i++) xs[i] = __shfl(x, gbase+i, 64);
    const float* wi = &sWih[t*FF*27];
    const float* wh = &sWhh[t*FF*27];
    float gir = sbih[t*27+f], giz = sbih[t*27+9+f], gin = sbih[t*27+18+f];
    float ghr = sbhh[t*27+f], ghz = sbhh[t*27+9+f], ghn = sbhh[t*27+18+f];
    #pragma unroll
    for(int i=0;i<FF;i++){
      float xi = xs[i], hi = hs[i];
      gir += xi*wi[i*27+f];    giz += xi*wi[i*27+9+f];    gin += xi*wi[i*27+18+f];
      ghr += hi*wh[i*27+f];    ghz += hi*wh[i*27+9+f];    ghn += hi*wh[i*27+18+f];
    }
    float r = 1.f/(1.f+__expf(-(gir+ghr)));
    float z = 1.f/(1.f+__expf(-(giz+ghz)));
    float nv = tanhf(gin + r*ghn);
    h = (1.f-z)*nv + z*h;
    #pragma unroll
    for(int i=0;i<FF;i++) hs[i] = __shfl(h, gbase+i, 64);
    if(valid && f == 0){
      float acc = cb;
      #pragma unroll
      for(int i=0;i<FF;i++) acc += hs[i]*c9[i];
      size_t gidx = (size_t)(b*TT+t)*NN + n;
      float m = (g[gidx*FF] != 0.f) ? 1.f : 0.f;
      out[gidx] = acc*m;
    }
  }
}

extern "C" void kernel_launch(void* const* d_in, const int* in_sizes, int n_in,
                              void* d_out, int out_size, void* d_ws, size_t ws_size,
                              hipStream_t stream){
  const float* g    = (const float*)d_in[0];
  const float* te   = (const float*)d_in[1];
  const float* ew   = (const float*)d_in[3];
  const int* esrc = (const int*)d_in[4];
  const int* edst = (const int*)d_in[5];
  const float* W1l=(const float*)d_in[6];  const float* b1 =(const float*)d_in[7];  const float* W1r=(const float*)d_in[8];
  const float* W2l=(const float*)d_in[9];  const float* b2 =(const float*)d_in[10]; const float* W2r=(const float*)d_in[11];
  const float* W3l=(const float*)d_in[12]; const float* b3 =(const float*)d_in[13]; const float* W3r=(const float*)d_in[14];
  const float* Wih=(const float*)d_in[15]; const float* Whh=(const float*)d_in[16];
  const float* bih=(const float*)d_in[17]; const float* bhh=(const float*)d_in[18];
  const float* encW=(const float*)d_in[19]; const float* encb=(const float*)d_in[20];
  const float* decW=(const float*)d_in[21]; const float* decb=(const float*)d_in[22];
  float* out = (float*)d_out;

  k_zero <<<(NN+255)/256, 256, 0, stream>>>();
  k_count_pack<<<((long)TT*NN*FF+255)/256, 256, 0, stream>>>(edst, g);
  k_scan <<<1, 256, 0, stream>>>(encW, encb, decW, decb, te);
  k_fill <<<(EE+255)/256, 256, 0, stream>>>(edst, esrc, ew);

  dim3 ggm((NN+63)/64, TT);
  k_agg1<<<2048, 256, 0, stream>>>();
  k_gemm1<<<ggm, 256, 0, stream>>>(W1l, b1, W1r);
  k_agg_all<<<2048, 256, 0, stream>>>();
  k_gemm23<<<ggm, 256, 0, stream>>>(W2l, b2, W2r, W3l, b3, W3r);
  k_agg9f<<<2048, 256, 0, stream>>>();
  // pairs = BB*NN; 28 pairs per 256-thread block (4 waves x 7)
  int nblk = (BB*NN + 27) / 28;
  k_gru_fused<<<nblk, 256, 0, stream>>>(g, Wih, Whh, bih, bhh, out);
}